// Round 13
// baseline (730.653 us; speedup 1.0000x reference)
//
#include <hip/hip_runtime.h>
#include <hip/hip_cooperative_groups.h>

namespace cg = cooperative_groups;

#define N_NODES 100000
#define DIM 128
#define N_REL 8
#define N_EDGES 625000
#define RN 800000            // N_REL * N_NODES (keys r*N+d)
#define N_PADROWS 100032     // 3126 blocks * 32 rows
#define PRE_BLOCKS 1024      // cooperative grid: 4 blocks/CU guaranteed co-resident
#define PRE_THREADS (PRE_BLOCKS * 256)

// fp32 -> bf16, round-to-nearest-even
__device__ __forceinline__ unsigned short f2bf(float f) {
    unsigned int u = __float_as_uint(f);
    u += 0x7fffu + ((u >> 16) & 1u);
    return (unsigned short)(u >> 16);
}

__device__ __forceinline__ float bf2f(unsigned short s) {
    return __uint_as_float(((unsigned int)s) << 16);
}

// ONE cooperative kernel replacing memset+prep+scan+fill (4 dispatch boundaries,
// ~12-20us each per r6/r7 cross-pipeline evidence) with 4 grid.sync()s (~2-5us):
//  A: zero degi | x->bf16 | pad rows | W->frag order       (grid-stride)
//  B: (rel,dst) histogram + per-edge rank                  (grid-stride)
//  C: exclusive scan degi[RN]->offs (block sums -> partials -> redundant
//     partial-scan in every block -> write)                (1024 elems/block)
//  D: scatter edges to ebuf by offs[key]+rank              (grid-stride)
__global__ __launch_bounds__(256, 4) void pre_kernel(const float* __restrict__ x,
                                                     const float* __restrict__ relw,
                                                     const float* __restrict__ selfw,
                                                     const int* __restrict__ src,
                                                     const int* __restrict__ dst,
                                                     const int* __restrict__ rel,
                                                     unsigned short* __restrict__ xb,
                                                     unsigned short* __restrict__ Wt,
                                                     int* __restrict__ degi,
                                                     int* __restrict__ rank,
                                                     int* __restrict__ offs,
                                                     unsigned int* __restrict__ ebuf,
                                                     int* __restrict__ partials) {
    cg::grid_group grid = cg::this_grid();
    __shared__ int lsum[256];
    __shared__ int gpx[256];
    const int tid = threadIdx.x;
    const int gtid = blockIdx.x * 256 + tid;

    // ---- phase A ----
    for (int i = gtid; i < RN / 4; i += PRE_THREADS) {   // zero degi (800000 ints)
        int4 z = {0, 0, 0, 0};
        ((int4*)degi)[i] = z;
    }
    for (int i = gtid; i < 3200000; i += PRE_THREADS) {  // x -> bf16, 4 elems/iter
        float4 v = ((const float4*)x)[i];
        unsigned short t[4] = {f2bf(v.x), f2bf(v.y), f2bf(v.z), f2bf(v.w)};
        *(uint2*)(xb + (size_t)i * 4) = *(const uint2*)t;
    }
    if (gtid < 512) {  // zero pad rows 100000..100031
        uint4 z = {0, 0, 0, 0};
        *(uint4*)(xb + (size_t)N_NODES * DIM + gtid * 8) = z;
    }
    if (gtid < 147456) {  // Wt[(((r*4+ks)*8+t)*64+lane)*8+j] = W_r[din=ks*32+q*8+j][dout=t*16+m16]
        int j = gtid & 7;
        int lane = (gtid >> 3) & 63;
        int t = (gtid >> 9) & 7;
        int ks = (gtid >> 12) & 3;
        int r = gtid >> 14;
        int m16 = lane & 15, quad = lane >> 4;
        int din = ks * 32 + quad * 8 + j;
        int dout = t * 16 + m16;
        float v = (r < 8) ? relw[(r << 14) + (din << 7) + dout] : selfw[(din << 7) + dout];
        Wt[gtid] = f2bf(v);
    }
    grid.sync();

    // ---- phase B: histogram + rank ----
    for (int e = gtid; e < N_EDGES; e += PRE_THREADS)
        rank[e] = atomicAdd(&degi[rel[e] * N_NODES + dst[e]], 1);
    grid.sync();

    // ---- phase C: exclusive scan (block = 1024 elements, thread = 4) ----
    {
        int base = blockIdx.x * 1024 + tid * 4;
        int4 d = {0, 0, 0, 0};
        if (base + 3 < RN) d = *(const int4*)(degi + base);
        else {
            if (base < RN) d.x = degi[base];
            if (base + 1 < RN) d.y = degi[base + 1];
            if (base + 2 < RN) d.z = degi[base + 2];
        }
        int s = d.x + d.y + d.z + d.w;
        lsum[tid] = s;
        __syncthreads();
        for (int off = 1; off < 256; off <<= 1) {
            int p = (tid >= off) ? lsum[tid - off] : 0;
            __syncthreads();
            lsum[tid] += p;
            __syncthreads();
        }
        int thrbase = lsum[tid] - s;
        if (tid == 255) partials[blockIdx.x] = lsum[255];
        grid.sync();

        // every block redundantly scans the 1024 partials for its own prefix
        int q0 = partials[tid * 4], q1 = partials[tid * 4 + 1];
        int q2 = partials[tid * 4 + 2], q3 = partials[tid * 4 + 3];
        int qs = q0 + q1 + q2 + q3;
        __syncthreads();
        lsum[tid] = qs;
        __syncthreads();
        for (int off = 1; off < 256; off <<= 1) {
            int p = (tid >= off) ? lsum[tid - off] : 0;
            __syncthreads();
            lsum[tid] += p;
            __syncthreads();
        }
        gpx[tid] = lsum[tid] - qs;
        __syncthreads();
        int b = blockIdx.x;
        int bpfx = gpx[b >> 2];
        int g4 = (b >> 2) * 4;
        if ((b & 3) > 0) bpfx += partials[g4];
        if ((b & 3) > 1) bpfx += partials[g4 + 1];
        if ((b & 3) > 2) bpfx += partials[g4 + 2];

        int run = bpfx + thrbase;
        if (base < RN)     { offs[base]     = run; if (base == RN - 1)     offs[RN] = run + d.x; run += d.x; }
        if (base + 1 < RN) { offs[base + 1] = run; if (base + 1 == RN - 1) offs[RN] = run + d.y; run += d.y; }
        if (base + 2 < RN) { offs[base + 2] = run; if (base + 2 == RN - 1) offs[RN] = run + d.z; run += d.z; }
        if (base + 3 < RN) { offs[base + 3] = run; if (base + 3 == RN - 1) offs[RN] = run + d.w; run += d.w; }
    }
    grid.sync();

    // ---- phase D: scatter edges (slot word = src | (d&15)<<17) ----
    for (int e = gtid; e < N_EDGES; e += PRE_THREADS) {
        int d = dst[e];
        int key = rel[e] * N_NODES + d;
        int pos = offs[key] + rank[e];
        ebuf[pos] = (unsigned int)src[e] | ((unsigned int)(d & 15) << 17);
    }
}

typedef __attribute__((ext_vector_type(8))) short frag8;
typedef __attribute__((ext_vector_type(4))) float f32x4;

// Fused aggregate+transform == round-12's verified ~100us kernel, UNCHANGED.
//  16-deep row-load batches; block = 32 dst rows, 4 waves (g=row-group, h=rel-
//  group), offs 2 rels ahead, edge words 1 rel ahead, first batch of r+1 issued
//  before r's MFMA, 16KB LDS, launch_bounds(256,4).
__global__ __launch_bounds__(256, 4) void fused_kernel(const unsigned short* __restrict__ xb,
                                                       const unsigned short* __restrict__ Wt,
                                                       const int* __restrict__ offs2,
                                                       const unsigned int* __restrict__ ebuf,
                                                       const float* __restrict__ bias,
                                                       float* __restrict__ out) {
    __shared__ __align__(16) unsigned char ldsraw[16384];

    const int tid = threadIdx.x;
    const int wave = tid >> 6, lane = tid & 63;
    const int g = wave >> 1, h = wave & 1;
    const int m16 = lane & 15, quad = lane >> 4;
    const int dbase = blockIdx.x * 32 + g * 16;
    unsigned char* slab = ldsraw + wave * 4096;
    const unsigned int* xb32 = (const unsigned int*)xb;

    int cidx = dbase + lane;
    if (cidx > N_NODES) cidx = N_NODES;
    const int* obase = offs2 + (size_t)h * 4 * N_NODES + cidx;

    // descriptors for this wave's first two relations, issued up-front
    int obc = obase[0];
    int obn = obase[N_NODES];

    f32x4 acc[8];
#pragma unroll
    for (int t = 0; t < 8; t++) acc[t] = (f32x4){0.f, 0.f, 0.f, 0.f};

    // relation-0 state + edge-word prefetch (issue before selfloop so it arrives under it)
    int s0 = __builtin_amdgcn_readlane(obc, 0);
    int count = __builtin_amdgcn_readlane(obc, 16) - s0;
    unsigned int ewc = 0;
    if (lane < count) ewc = ebuf[s0 + lane];

    if (h == 0) {
        // ---- selfloop: A-frags direct from xb (pad rows zeroed); hides ew latency ----
        const unsigned short* ap = xb + (size_t)(dbase + m16) * DIM;
#pragma unroll
        for (int ks = 0; ks < 4; ks++) {
            frag8 a = *(const frag8*)(ap + ks * 32 + quad * 8);
            const frag8* bp = (const frag8*)Wt + ((8 * 4 + ks) * 8) * 64 + lane;
#pragma unroll
            for (int t = 0; t < 8; t++)
                acc[t] = __builtin_amdgcn_mfma_f32_16x16x32_bf16(a, bp[t * 64], acc[t], 0, 0, 0);
        }
    }

    // preload relation 0's first 16-deep row batch
    unsigned int u0[16], v0[16];
    if (count > 0) {
        int cl = count; if (cl > 64) cl = 64;
#pragma unroll
        for (int k = 0; k < 16; k++) {
            int li = k; if (li >= cl) li = cl - 1;
            u0[k] = (unsigned int)__builtin_amdgcn_readlane((int)ewc, li);
            v0[k] = xb32[(size_t)(u0[k] & 0x1ffffu) * 64 + lane];
        }
    }

#pragma unroll 1
    for (int r = 0; r < 4; r++) {
        // prefetch chain: r+1 edge words (offs already resident), r+2 offs
        int s0n = __builtin_amdgcn_readlane(obn, 0);
        int cntn = __builtin_amdgcn_readlane(obn, 16) - s0n;
        unsigned int ewn = 0;
        if (r < 3 && lane < cntn) ewn = ebuf[s0n + lane];
        int obn2 = (r < 2) ? obase[(r + 2) * N_NODES] : 0;

        // pre-zero the 4KB tile (empty segments stay zero)
        {
            uint4 z = {0, 0, 0, 0};
            *(uint4*)(slab + lane * 16) = z;
            *(uint4*)(slab + 1024 + lane * 16) = z;
            *(uint4*)(slab + 2048 + lane * 16) = z;
            *(uint4*)(slab + 3072 + lane * 16) = z;
        }

        if (count > 0) {
            float ax = 0.f, ay = 0.f;
            int cur = -1, cnt = 0;
#pragma unroll 1
            for (int b0 = 0; b0 < count; b0 += 64) {
                int cl = count - b0; if (cl > 64) cl = 64;
                unsigned int ew = ewc;
                if (b0 > 0) {            // rare (count>64): refill edge words inline
                    ew = 0;
                    if (b0 + lane < count) ew = ebuf[s0 + b0 + lane];
                }
#pragma unroll 1
                for (int i = 0; i < cl; i += 16) {
                    if (b0 + i > 0) {    // refill batch inline (13% of segments)
#pragma unroll
                        for (int k = 0; k < 16; k++) {
                            int li = i + k; if (li >= cl) li = cl - 1;
                            u0[k] = (unsigned int)__builtin_amdgcn_readlane((int)ew, li);
                            v0[k] = xb32[(size_t)(u0[k] & 0x1ffffu) * 64 + lane];
                        }
                    }
                    int kk = cl - i; if (kk > 16) kk = 16;
#pragma unroll
                    for (int k = 0; k < 16; k++) {
                        if (k < kk) {                    // wave-uniform guard
                            int dl = (int)((u0[k] >> 17) & 15u);
                            if (dl != cur) {
                                if (cnt > 0) {
                                    float inv = __builtin_amdgcn_rcpf((float)cnt);
                                    unsigned int p = (unsigned int)f2bf(ax * inv) |
                                                     ((unsigned int)f2bf(ay * inv) << 16);
                                    int bb = (lane >> 2) ^ cur;
                                    *(unsigned int*)(slab + cur * 256 + bb * 16 + (lane & 3) * 4) = p;
                                }
                                cur = dl; ax = 0.f; ay = 0.f; cnt = 0;
                            }
                            ax += bf2f((unsigned short)(v0[k] & 0xffffu));
                            ay += bf2f((unsigned short)(v0[k] >> 16));
                            cnt++;
                        }
                    }
                }
            }
            {   // final flush (cnt>0 since count>0)
                float inv = __builtin_amdgcn_rcpf((float)cnt);
                unsigned int p = (unsigned int)f2bf(ax * inv) |
                                 ((unsigned int)f2bf(ay * inv) << 16);
                int bb = (lane >> 2) ^ cur;
                *(unsigned int*)(slab + cur * 256 + bb * 16 + (lane & 3) * 4) = p;
            }
        }

        // preload r+1's first 16-deep batch NOW so its latency hides under the MFMA
        if (r < 3 && cntn > 0) {
            int cl = cntn; if (cl > 64) cl = 64;
#pragma unroll
            for (int k = 0; k < 16; k++) {
                int li = k; if (li >= cl) li = cl - 1;
                u0[k] = (unsigned int)__builtin_amdgcn_readlane((int)ewn, li);
                v0[k] = xb32[(size_t)(u0[k] & 0x1ffffu) * 64 + lane];
            }
        }

        // A-frags from swizzled tile + MFMA (LDS ops in-order per wave; no barrier)
#pragma unroll
        for (int ks = 0; ks < 4; ks++) {
            int bb = (4 * ks + quad) ^ m16;
            frag8 a = *(const frag8*)(slab + m16 * 256 + bb * 16);
            const frag8* bp = (const frag8*)Wt + (((h * 4 + r) * 4 + ks) * 8) * 64 + lane;
#pragma unroll
            for (int t = 0; t < 8; t++)
                acc[t] = __builtin_amdgcn_mfma_f32_16x16x32_bf16(a, bp[t * 64], acc[t], 0, 0, 0);
        }

        // rotate relation state
        s0 = s0n; count = cntn; ewc = ewn; obn = obn2;
    }

    // ---- merge rel-halves: h=1 waves publish acc via LDS (reusing gather slabs) ----
    __syncthreads();
    unsigned char* mbuf = ldsraw + g * 8192;
    if (h == 1) {
#pragma unroll
        for (int t = 0; t < 8; t++)
            *(f32x4*)(mbuf + (t * 64 + lane) * 16) = acc[t];
    }
    __syncthreads();
    if (h == 0) {
#pragma unroll
        for (int t = 0; t < 8; t++) {
            f32x4 m = *(f32x4*)(mbuf + (t * 64 + lane) * 16);
            acc[t] += m;
        }

        // ---- epilogue: +bias, two column-halves through mbuf (wave-private now;
        // own reads above are LDS-ordered before these writes)
        float* S = (float*)mbuf;
#pragma unroll
        for (int hh = 0; hh < 2; hh++) {
#pragma unroll
            for (int tt = 0; tt < 4; tt++) {
                int t = hh * 4 + tt;
                float bc = bias[t * 16 + m16];
#pragma unroll
                for (int i = 0; i < 4; i++)
                    S[(quad * 4 + i) * 68 + tt * 16 + m16] = acc[t][i] + bc;
            }
#pragma unroll
            for (int c = 0; c < 4; c++) {
                int row16 = c * 4 + quad;
                int gr = dbase + row16;
                if (gr < N_NODES)
                    *(float4*)(out + (size_t)gr * DIM + hh * 64 + m16 * 4) =
                        *(float4*)(S + row16 * 68 + m16 * 4);
            }
        }
    }
}

extern "C" void kernel_launch(void* const* d_in, const int* in_sizes, int n_in,
                              void* d_out, int out_size, void* d_ws, size_t ws_size,
                              hipStream_t stream) {
    const float* x = (const float*)d_in[0];
    const int* edge_index = (const int*)d_in[1]; // [2][E]: src then dst
    const int* edge_type = (const int*)d_in[2];
    const float* relw = (const float*)d_in[3];
    const float* selfw = (const float*)d_in[4];
    const float* bias = (const float*)d_in[5];
    float* out = (float*)d_out;
    (void)in_sizes; (void)n_in; (void)out_size; (void)ws_size;

    // ws: xb 25.6MB | Wt 0.29MB | offs2 3.2MB | ebuf 2.5MB | partials 4KB
    char* ws = (char*)d_ws;
    size_t off = 0;
    unsigned short* xb = (unsigned short*)(ws + off); off += (size_t)N_PADROWS * DIM * 2;
    unsigned short* Wt = (unsigned short*)(ws + off); off += (size_t)9 * DIM * DIM * 2;
    int* offs2 = (int*)(ws + off); off += (size_t)(RN + 4) * 4;
    unsigned int* ebuf = (unsigned int*)(ws + off); off += (size_t)N_EDGES * 4;
    int* partials = (int*)(ws + off); off += (size_t)PRE_BLOCKS * 4;

    // pre-fused scratch in d_out (fused_kernel overwrites all of out at the end):
    // degi[RN] | rank[N_EDGES]  (~5.7MB << 51.2MB)
    int* degi = (int*)d_out;
    int* rank = degi + RN;

    const int* src = edge_index;
    const int* dst = edge_index + N_EDGES;

    void* args[] = {(void*)&x, (void*)&relw, (void*)&selfw, (void*)&src, (void*)&dst,
                    (void*)&edge_type, (void*)&xb, (void*)&Wt, (void*)&degi, (void*)&rank,
                    (void*)&offs2, (void*)&ebuf, (void*)&partials};
    hipLaunchCooperativeKernel((void*)pre_kernel, dim3(PRE_BLOCKS), dim3(256),
                               args, 0, stream);
    fused_kernel<<<N_PADROWS / 32, 256, 0, stream>>>(xb, Wt, offs2, ebuf, bias, out);
}

// Round 14
// 251.134 us; speedup vs baseline: 2.9094x; 2.9094x over previous
//
#include <hip/hip_runtime.h>

#define N_NODES 100000
#define DIM 128
#define N_REL 8
#define N_EDGES 625000
#define RN 800000            // N_REL * N_NODES (keys r*N+d)
#define N_PADROWS 100032     // 3126 blocks * 32 rows
#define SCAN_BLOCKS 98
#define SCAN_CHUNK 8192      // 256 threads * 32 elems

// fp32 -> bf16, round-to-nearest-even
__device__ __forceinline__ unsigned short f2bf(float f) {
    unsigned int u = __float_as_uint(f);
    u += 0x7fffu + ((u >> 16) & 1u);
    return (unsigned short)(u >> 16);
}

__device__ __forceinline__ float bf2f(unsigned short s) {
    return __uint_as_float(((unsigned int)s) << 16);
}

// prep: x->bf16 (12.8M elems, 4/thread, exact grid), zero xb pad rows,
// W -> MFMA B-frag order, (rel,dst) histogram + per-edge rank (degi pre-zeroed).
__global__ __launch_bounds__(256) void prep_kernel(const float* __restrict__ x,
                                                   const float* __restrict__ relw,
                                                   const float* __restrict__ selfw,
                                                   const int* __restrict__ dst,
                                                   const int* __restrict__ rel,
                                                   unsigned short* __restrict__ xb,
                                                   unsigned short* __restrict__ Wt,
                                                   int* __restrict__ degi,
                                                   int* __restrict__ rank) {
    int i = blockIdx.x * 256 + threadIdx.x;      // 0 .. 3,199,999 exact
    {
        float4 v = *(const float4*)(x + (size_t)i * 4);
        unsigned short t[4] = {f2bf(v.x), f2bf(v.y), f2bf(v.z), f2bf(v.w)};
        *(uint2*)(xb + (size_t)i * 4) = *(const uint2*)t;
    }
    if (i < 512) {  // zero pad rows 100000..100031
        uint4 z = {0, 0, 0, 0};
        *(uint4*)(xb + (size_t)N_NODES * DIM + i * 8) = z;
    }
    if (i < 147456) {  // Wt[(((r*4+ks)*8+t)*64+lane)*8+j] = W_r[din=ks*32+quad*8+j][dout=t*16+m16]
        int j = i & 7;
        int lane = (i >> 3) & 63;
        int t = (i >> 9) & 7;
        int ks = (i >> 12) & 3;
        int r = i >> 14;
        int m16 = lane & 15, quad = lane >> 4;
        int din = ks * 32 + quad * 8 + j;
        int dout = t * 16 + m16;
        float v = (r < 8) ? relw[(r << 14) + (din << 7) + dout] : selfw[(din << 7) + dout];
        Wt[i] = f2bf(v);
    }
    if (i < N_EDGES) {
        // rank within (rel,dst) segment; removes the atomic pass from fill_kernel
        rank[i] = atomicAdd(&degi[rel[i] * N_NODES + dst[i]], 1);
    }
}

// Single-pass exclusive scan of degi[RN] -> offs, wave-parallel lookback.
// 98 blocks are all co-resident (<< 256 CUs) so spinning on blockIdx order is safe.
// status word: bit31=prefix-ready, bit30=aggregate-ready, low 30 bits = value.
__global__ __launch_bounds__(256) void scan_kernel(const int* __restrict__ degi,
                                                   unsigned int* __restrict__ status,
                                                   int* __restrict__ offs) {
    __shared__ int lsum[256];
    __shared__ int lpfx;
    const int tid = threadIdx.x;
    const int b = blockIdx.x;
    const int base = b * SCAN_CHUNK + tid * 32;
    int v[32];
    int s = 0;
#pragma unroll
    for (int j = 0; j < 8; j++) {
        int idx = base + j * 4;
        int4 d = {0, 0, 0, 0};
        if (idx + 3 < RN) d = *(const int4*)(degi + idx);
        else {
            if (idx < RN) d.x = degi[idx];
            if (idx + 1 < RN) d.y = degi[idx + 1];
            if (idx + 2 < RN) d.z = degi[idx + 2];
        }
        v[j * 4] = d.x; v[j * 4 + 1] = d.y; v[j * 4 + 2] = d.z; v[j * 4 + 3] = d.w;
        s += d.x + d.y + d.z + d.w;
    }
    lsum[tid] = s;
    __syncthreads();
    for (int off = 1; off < 256; off <<= 1) {
        int p = (tid >= off) ? lsum[tid - off] : 0;
        __syncthreads();
        lsum[tid] += p;
        __syncthreads();
    }
    int thrbase = lsum[tid] - s;
    int total = lsum[255];

    if (b == 0) {
        if (tid == 0) {
            atomicExch(&status[0], 0x80000000u | (unsigned)total);
            lpfx = 0;
        }
    } else {
        if (tid == 0) atomicExch(&status[b], 0x40000000u | (unsigned)total);
        if (tid < 64) {
            int sum = 0;
            int j = b - 1;
            while (true) {
                int idx = j - tid;
                unsigned st = (idx >= 0) ? atomicAdd(&status[idx], 0u) : 0x80000000u;
                unsigned long long pball = __ballot(st & 0x80000000u);
                unsigned long long zball = __ballot(st == 0u);
                int fp = pball ? (__ffsll(pball) - 1) : 64;
                unsigned long long below = (fp >= 64) ? ~0ull : ((1ull << fp) - 1ull);
                if (zball & below) continue;         // gap not ready yet, re-read
                int lim = (fp < 64) ? fp : 63;
                int val = (tid <= lim) ? (int)(st & 0x3fffffffu) : 0;
                for (int o = 32; o > 0; o >>= 1) val += __shfl_down(val, o);
                sum += __shfl(val, 0);
                if (fp < 64) break;
                j -= 64;
            }
            if (tid == 0) {
                atomicExch(&status[b], 0x80000000u | (unsigned)(sum + total));
                lpfx = sum;
            }
        }
    }
    __syncthreads();
    int run = lpfx + thrbase;
#pragma unroll
    for (int j = 0; j < 32; j++) {
        int idx = base + j;
        if (idx < RN) {
            offs[idx] = run;
            if (idx == RN - 1) offs[RN] = run + v[j];
            run += v[j];
        }
    }
}

// Bin edges by key r*N+d using precomputed rank (no atomics).
// slot word = src | (d&15)<<17 (deg = segment length).
__global__ __launch_bounds__(256) void fill_kernel(const int* __restrict__ src,
                                                   const int* __restrict__ dst,
                                                   const int* __restrict__ rel,
                                                   const int* __restrict__ rank,
                                                   const int* __restrict__ offs,
                                                   unsigned int* __restrict__ ebuf) {
    int e = blockIdx.x * 256 + threadIdx.x;
    if (e < N_EDGES) {
        int d = dst[e];
        int key = rel[e] * N_NODES + d;
        int pos = offs[key] + rank[e];
        ebuf[pos] = (unsigned int)src[e] | ((unsigned int)(d & 15) << 17);
    }
}

typedef __attribute__((ext_vector_type(8))) short frag8;
typedef __attribute__((ext_vector_type(4))) float f32x4;

// Fused aggregate+transform == round-12's verified ~100us kernel, byte-identical.
//  16-deep row-load batches (covers 87% of segments in one MFMA-hidden burst);
//  block = 32 dst rows, 4 waves (g=row-group, h=rel-group), offs 2 rels ahead,
//  edge words 1 rel ahead, first batch of r+1 issued before r's MFMA, 16KB LDS,
//  launch_bounds(256,4). Session ledger of measured-dead alternatives: forced
//  occupancy (r1/r4: spills), LDS-direct DMA (r5), LDS atomics (r6), register
//  scatter (r7), in-wave sort (r8), setprio/selfloop-split (r9), column-split
//  pairs (r11), cooperative pre-fusion (r13: grid.sync ~100us each).
__global__ __launch_bounds__(256, 4) void fused_kernel(const unsigned short* __restrict__ xb,
                                                       const unsigned short* __restrict__ Wt,
                                                       const int* __restrict__ offs2,
                                                       const unsigned int* __restrict__ ebuf,
                                                       const float* __restrict__ bias,
                                                       float* __restrict__ out) {
    __shared__ __align__(16) unsigned char ldsraw[16384];

    const int tid = threadIdx.x;
    const int wave = tid >> 6, lane = tid & 63;
    const int g = wave >> 1, h = wave & 1;
    const int m16 = lane & 15, quad = lane >> 4;
    const int dbase = blockIdx.x * 32 + g * 16;
    unsigned char* slab = ldsraw + wave * 4096;
    const unsigned int* xb32 = (const unsigned int*)xb;

    int cidx = dbase + lane;
    if (cidx > N_NODES) cidx = N_NODES;
    const int* obase = offs2 + (size_t)h * 4 * N_NODES + cidx;

    // descriptors for this wave's first two relations, issued up-front
    int obc = obase[0];
    int obn = obase[N_NODES];

    f32x4 acc[8];
#pragma unroll
    for (int t = 0; t < 8; t++) acc[t] = (f32x4){0.f, 0.f, 0.f, 0.f};

    // relation-0 state + edge-word prefetch (issue before selfloop so it arrives under it)
    int s0 = __builtin_amdgcn_readlane(obc, 0);
    int count = __builtin_amdgcn_readlane(obc, 16) - s0;
    unsigned int ewc = 0;
    if (lane < count) ewc = ebuf[s0 + lane];

    if (h == 0) {
        // ---- selfloop: A-frags direct from xb (pad rows zeroed); hides ew latency ----
        const unsigned short* ap = xb + (size_t)(dbase + m16) * DIM;
#pragma unroll
        for (int ks = 0; ks < 4; ks++) {
            frag8 a = *(const frag8*)(ap + ks * 32 + quad * 8);
            const frag8* bp = (const frag8*)Wt + ((8 * 4 + ks) * 8) * 64 + lane;
#pragma unroll
            for (int t = 0; t < 8; t++)
                acc[t] = __builtin_amdgcn_mfma_f32_16x16x32_bf16(a, bp[t * 64], acc[t], 0, 0, 0);
        }
    }

    // preload relation 0's first 16-deep row batch
    unsigned int u0[16], v0[16];
    if (count > 0) {
        int cl = count; if (cl > 64) cl = 64;
#pragma unroll
        for (int k = 0; k < 16; k++) {
            int li = k; if (li >= cl) li = cl - 1;
            u0[k] = (unsigned int)__builtin_amdgcn_readlane((int)ewc, li);
            v0[k] = xb32[(size_t)(u0[k] & 0x1ffffu) * 64 + lane];
        }
    }

#pragma unroll 1
    for (int r = 0; r < 4; r++) {
        // prefetch chain: r+1 edge words (offs already resident), r+2 offs
        int s0n = __builtin_amdgcn_readlane(obn, 0);
        int cntn = __builtin_amdgcn_readlane(obn, 16) - s0n;
        unsigned int ewn = 0;
        if (r < 3 && lane < cntn) ewn = ebuf[s0n + lane];
        int obn2 = (r < 2) ? obase[(r + 2) * N_NODES] : 0;

        // pre-zero the 4KB tile (empty segments stay zero)
        {
            uint4 z = {0, 0, 0, 0};
            *(uint4*)(slab + lane * 16) = z;
            *(uint4*)(slab + 1024 + lane * 16) = z;
            *(uint4*)(slab + 2048 + lane * 16) = z;
            *(uint4*)(slab + 3072 + lane * 16) = z;
        }

        if (count > 0) {
            float ax = 0.f, ay = 0.f;
            int cur = -1, cnt = 0;
#pragma unroll 1
            for (int b0 = 0; b0 < count; b0 += 64) {
                int cl = count - b0; if (cl > 64) cl = 64;
                unsigned int ew = ewc;
                if (b0 > 0) {            // rare (count>64): refill edge words inline
                    ew = 0;
                    if (b0 + lane < count) ew = ebuf[s0 + b0 + lane];
                }
#pragma unroll 1
                for (int i = 0; i < cl; i += 16) {
                    if (b0 + i > 0) {    // refill batch inline (13% of segments)
#pragma unroll
                        for (int k = 0; k < 16; k++) {
                            int li = i + k; if (li >= cl) li = cl - 1;
                            u0[k] = (unsigned int)__builtin_amdgcn_readlane((int)ew, li);
                            v0[k] = xb32[(size_t)(u0[k] & 0x1ffffu) * 64 + lane];
                        }
                    }
                    int kk = cl - i; if (kk > 16) kk = 16;
#pragma unroll
                    for (int k = 0; k < 16; k++) {
                        if (k < kk) {                    // wave-uniform guard
                            int dl = (int)((u0[k] >> 17) & 15u);
                            if (dl != cur) {
                                if (cnt > 0) {
                                    float inv = __builtin_amdgcn_rcpf((float)cnt);
                                    unsigned int p = (unsigned int)f2bf(ax * inv) |
                                                     ((unsigned int)f2bf(ay * inv) << 16);
                                    int bb = (lane >> 2) ^ cur;
                                    *(unsigned int*)(slab + cur * 256 + bb * 16 + (lane & 3) * 4) = p;
                                }
                                cur = dl; ax = 0.f; ay = 0.f; cnt = 0;
                            }
                            ax += bf2f((unsigned short)(v0[k] & 0xffffu));
                            ay += bf2f((unsigned short)(v0[k] >> 16));
                            cnt++;
                        }
                    }
                }
            }
            {   // final flush (cnt>0 since count>0)
                float inv = __builtin_amdgcn_rcpf((float)cnt);
                unsigned int p = (unsigned int)f2bf(ax * inv) |
                                 ((unsigned int)f2bf(ay * inv) << 16);
                int bb = (lane >> 2) ^ cur;
                *(unsigned int*)(slab + cur * 256 + bb * 16 + (lane & 3) * 4) = p;
            }
        }

        // preload r+1's first 16-deep batch NOW so its latency hides under the MFMA
        if (r < 3 && cntn > 0) {
            int cl = cntn; if (cl > 64) cl = 64;
#pragma unroll
            for (int k = 0; k < 16; k++) {
                int li = k; if (li >= cl) li = cl - 1;
                u0[k] = (unsigned int)__builtin_amdgcn_readlane((int)ewn, li);
                v0[k] = xb32[(size_t)(u0[k] & 0x1ffffu) * 64 + lane];
            }
        }

        // A-frags from swizzled tile + MFMA (LDS ops in-order per wave; no barrier)
#pragma unroll
        for (int ks = 0; ks < 4; ks++) {
            int bb = (4 * ks + quad) ^ m16;
            frag8 a = *(const frag8*)(slab + m16 * 256 + bb * 16);
            const frag8* bp = (const frag8*)Wt + (((h * 4 + r) * 4 + ks) * 8) * 64 + lane;
#pragma unroll
            for (int t = 0; t < 8; t++)
                acc[t] = __builtin_amdgcn_mfma_f32_16x16x32_bf16(a, bp[t * 64], acc[t], 0, 0, 0);
        }

        // rotate relation state
        s0 = s0n; count = cntn; ewc = ewn; obn = obn2;
    }

    // ---- merge rel-halves: h=1 waves publish acc via LDS (reusing gather slabs) ----
    __syncthreads();
    unsigned char* mbuf = ldsraw + g * 8192;
    if (h == 1) {
#pragma unroll
        for (int t = 0; t < 8; t++)
            *(f32x4*)(mbuf + (t * 64 + lane) * 16) = acc[t];
    }
    __syncthreads();
    if (h == 0) {
#pragma unroll
        for (int t = 0; t < 8; t++) {
            f32x4 m = *(f32x4*)(mbuf + (t * 64 + lane) * 16);
            acc[t] += m;
        }

        // ---- epilogue: +bias, two column-halves through mbuf (wave-private now;
        // own reads above are LDS-ordered before these writes)
        float* S = (float*)mbuf;
#pragma unroll
        for (int hh = 0; hh < 2; hh++) {
#pragma unroll
            for (int tt = 0; tt < 4; tt++) {
                int t = hh * 4 + tt;
                float bc = bias[t * 16 + m16];
#pragma unroll
                for (int i = 0; i < 4; i++)
                    S[(quad * 4 + i) * 68 + tt * 16 + m16] = acc[t][i] + bc;
            }
#pragma unroll
            for (int c = 0; c < 4; c++) {
                int row16 = c * 4 + quad;
                int gr = dbase + row16;
                if (gr < N_NODES)
                    *(float4*)(out + (size_t)gr * DIM + hh * 64 + m16 * 4) =
                        *(float4*)(S + row16 * 68 + m16 * 4);
            }
        }
    }
}

extern "C" void kernel_launch(void* const* d_in, const int* in_sizes, int n_in,
                              void* d_out, int out_size, void* d_ws, size_t ws_size,
                              hipStream_t stream) {
    const float* x = (const float*)d_in[0];
    const int* edge_index = (const int*)d_in[1]; // [2][E]: src then dst
    const int* edge_type = (const int*)d_in[2];
    const float* relw = (const float*)d_in[3];
    const float* selfw = (const float*)d_in[4];
    const float* bias = (const float*)d_in[5];
    float* out = (float*)d_out;
    (void)in_sizes; (void)n_in; (void)out_size; (void)ws_size;

    // ws: xb 25.6MB | Wt 0.29MB | offs2 3.2MB | ebuf 2.5MB
    char* ws = (char*)d_ws;
    size_t off = 0;
    unsigned short* xb = (unsigned short*)(ws + off); off += (size_t)N_PADROWS * DIM * 2;
    unsigned short* Wt = (unsigned short*)(ws + off); off += (size_t)9 * DIM * DIM * 2;
    int* offs2 = (int*)(ws + off); off += (size_t)(RN + 4) * 4;
    unsigned int* ebuf = (unsigned int*)(ws + off); off += (size_t)N_EDGES * 4;

    // pre-fused scratch in d_out (fused_kernel overwrites all of out at the end):
    // degi[RN] | status[SCAN_BLOCKS+2] | rank[N_EDGES]  (total ~5.7MB << 51.2MB)
    int* degi = (int*)d_out;
    unsigned int* status = (unsigned int*)(degi + RN);
    int* rank = (int*)(status + SCAN_BLOCKS + 2);

    const int* src = edge_index;
    const int* dst = edge_index + N_EDGES;

    hipMemsetAsync(degi, 0, (size_t)RN * 4 + (SCAN_BLOCKS + 2) * 4, stream);
    prep_kernel<<<12500, 256, 0, stream>>>(x, relw, selfw, dst, edge_type, xb, Wt, degi, rank);
    scan_kernel<<<SCAN_BLOCKS, 256, 0, stream>>>(degi, status, offs2);
    fill_kernel<<<(N_EDGES + 255) / 256, 256, 0, stream>>>(src, dst, edge_type, rank, offs2, ebuf);
    fused_kernel<<<N_PADROWS / 32, 256, 0, stream>>>(xb, Wt, offs2, ebuf, bias, out);
}